// Round 2
// baseline (36.872 us; speedup 1.0000x reference)
//
#include <hip/hip_runtime.h>

// EmbeddingBag (SUM): out[b][d] = sum_k weight[input[b][k]][d]
// input: [16384, 50] int, weight: [1_000_000, 64] fp32, out: [16384, 64] fp32
//
// Structure: 16 threads per batch row, each owns one float4 (16 B) slice of
// the 64-dim row -> each gathered row is one contiguous 256 B segment read
// by a 16-lane group. Grid = 1024 blocks x 256 thr = 16 waves/CU.
// CHUNK=16 explicit prefetch: ~256 outstanding 256B requests per CU to give
// the memory controller a deep reorder window for DRAM page locality.

#define EB_BATCH 16384
#define EB_BAG 50
#define EB_DIM 64
#define EB_CHUNK 16

__global__ __launch_bounds__(256) void CompoundEmbedding_79989470921233_kernel(
    const int* __restrict__ idx, const float* __restrict__ weight,
    float* __restrict__ out) {
    const int tid = blockIdx.x * blockDim.x + threadIdx.x;  // 0 .. BATCH*16-1
    const int b  = tid >> 4;   // 16 threads per batch row
    const int dq = tid & 15;   // which float4 of the 64-dim row
    if (b >= EB_BATCH) return;

    const int* __restrict__ bag = idx + b * EB_BAG;
    const float* __restrict__ wq = weight + (dq << 2);  // this lane's 16B slice

    float4 acc = make_float4(0.f, 0.f, 0.f, 0.f);

    int k0 = 0;
    // Full chunks of EB_CHUNK
    for (; k0 + EB_CHUNK <= EB_BAG; k0 += EB_CHUNK) {
        int r[EB_CHUNK];
#pragma unroll
        for (int k = 0; k < EB_CHUNK; ++k) r[k] = bag[k0 + k];
        float4 v[EB_CHUNK];
#pragma unroll
        for (int k = 0; k < EB_CHUNK; ++k)
            v[k] = *reinterpret_cast<const float4*>(wq + (size_t)r[k] * EB_DIM);
#pragma unroll
        for (int k = 0; k < EB_CHUNK; ++k) {
            acc.x += v[k].x; acc.y += v[k].y; acc.z += v[k].z; acc.w += v[k].w;
        }
    }
    // Tail (EB_BAG % EB_CHUNK = 2)
    {
        int r[EB_BAG % EB_CHUNK];
#pragma unroll
        for (int k = 0; k < EB_BAG % EB_CHUNK; ++k) r[k] = bag[k0 + k];
        float4 v[EB_BAG % EB_CHUNK];
#pragma unroll
        for (int k = 0; k < EB_BAG % EB_CHUNK; ++k)
            v[k] = *reinterpret_cast<const float4*>(wq + (size_t)r[k] * EB_DIM);
#pragma unroll
        for (int k = 0; k < EB_BAG % EB_CHUNK; ++k) {
            acc.x += v[k].x; acc.y += v[k].y; acc.z += v[k].z; acc.w += v[k].w;
        }
    }

    reinterpret_cast<float4*>(out)[tid] = acc;  // byte offset b*256 + dq*16
}

extern "C" void kernel_launch(void* const* d_in, const int* in_sizes, int n_in,
                              void* d_out, int out_size, void* d_ws, size_t ws_size,
                              hipStream_t stream) {
    const int* idx = (const int*)d_in[0];          // input [16384, 50]
    const float* weight = (const float*)d_in[1];   // weight [1e6, 64]
    float* out = (float*)d_out;                    // [16384, 64]

    const int threads = 256;
    const int total = EB_BATCH * 16;               // 16 threads per batch row
    const int blocks = (total + threads - 1) / threads;  // 1024
    CompoundEmbedding_79989470921233_kernel<<<blocks, threads, 0, stream>>>(
        idx, weight, out);
}